// Round 3
// baseline (72.860 us; speedup 1.0000x reference)
//
#include <hip/hip_runtime.h>
#include <math.h>

// Problem constants (from reference setup_inputs)
constexpr int BS = 16;
constexpr int NQ = 100;
constexpr int JD = 51;
constexpr int JDP = 52;  // padded pjs row stride: 52*4=208 B, 16B-aligned rows
constexpr int NA = 8;    // action classes
constexpr int NI = 10;   // identity classes
constexpr int ITILE = 4;             // i-rows per block
constexpr int NTILES = NQ / ITILE;   // 25
constexpr int BLOCK = 128;           // 2 waves; thread = one j, all ITILE rows

// out[b,i,j] = -(t_j*log(p_i) + (1-t_j)*log(1-p_i))            (C_prob)
//            + sum_k |pred_joint[b,i,k] - tar_joint[b,j,k]|     (C_joint)
//            + CE(pred_action[b,i])[0] + CE(pred_identity[b,i])[0]
__global__ __launch_bounds__(BLOCK) void matcher_kernel(
    const float* __restrict__ pred_conf,    // [BS,NQ,1]
    const float* __restrict__ pred_joint,   // [BS,NQ,JD]
    const float* __restrict__ pred_action,  // [BS,NQ,NA]
    const float* __restrict__ pred_ident,   // [BS,NQ,NI]
    const float* __restrict__ tar_conf,     // [BS,NQ]
    const float* __restrict__ tar_joint,    // [BS,NQ,JD]
    float* __restrict__ out)                // [BS,NQ,NQ]
{
    const int b   = blockIdx.x;
    const int it  = blockIdx.y;
    const int i0  = it * ITILE;
    const int tid = threadIdx.x;

    // 20.4 KB: whole batch of target joint rows, stride 51 (19 mod 32,
    // gcd(19,32)=1 -> per-lane reads are 2 lanes/bank = conflict-free).
    __shared__ __align__(16) float tjs[NQ * JD];
    // pred rows padded to 52 so each row base is 16B-aligned -> b128 broadcasts.
    __shared__ __align__(16) float pjs[ITILE * JDP];
    __shared__ float lps[ITILE];         // log(sigmoid(conf_i))
    __shared__ float l1ps[ITILE];        // log(1 - sigmoid(conf_i))
    __shared__ float rowc[ITILE];        // ce_action + ce_identity per i

    // --- cooperative float4 staging of tar_joint (base b*20400 is 16B-mult) ---
    {
        const float4* tj4 = (const float4*)(tar_joint + (size_t)b * NQ * JD);
        float4* tjs4 = (float4*)tjs;
        #pragma unroll
        for (int idx = tid; idx < (NQ * JD) / 4; idx += BLOCK)  // 1275 vec4
            tjs4[idx] = tj4[idx];
    }
    // pred rows: 4 rows x 51 floats, scalar stage into padded layout (204 elems)
    {
        const float* pj_g = pred_joint + ((size_t)b * NQ + i0) * JD;
        for (int idx = tid; idx < ITILE * JD; idx += BLOCK) {
            int r = idx / JD, c = idx - r * JD;
            pjs[r * JDP + c] = pj_g[idx];
        }
    }

    // --- per-i row terms (ITILE threads) ---
    if (tid < ITILE) {
        const int row = b * NQ + i0 + tid;
        float x  = pred_conf[row];
        // log(sigmoid(x)) = -log1p(exp(-x)); log(1-sigmoid(x)) = that - x
        float lp = -log1pf(__expf(-x));
        lps[tid]  = lp;
        l1ps[tid] = lp - x;

        const float* a = pred_action + (size_t)row * NA;
        float m = a[0];
        #pragma unroll
        for (int k = 1; k < NA; k++) m = fmaxf(m, a[k]);
        float s = 0.f;
        #pragma unroll
        for (int k = 0; k < NA; k++) s += __expf(a[k] - m);
        float cea = __logf(s) + m - a[0];

        const float* pi = pred_ident + (size_t)row * NI;
        float m2 = pi[0];
        #pragma unroll
        for (int k = 1; k < NI; k++) m2 = fmaxf(m2, pi[k]);
        float s2 = 0.f;
        #pragma unroll
        for (int k = 0; k < NI; k++) s2 += __expf(pi[k] - m2);
        float cei = __logf(s2) + m2 - pi[0];

        rowc[tid] = cea + cei;
    }
    __syncthreads();

    // --- compute: thread owns column j and sweeps all ITILE rows ---
    const int j = tid;               // 0..127 (j<NQ active)
    if (j < NQ) {
        // target row into registers (one-time, conflict-free stride-51 reads)
        float tj[JD];
        #pragma unroll
        for (int k = 0; k < JD; k++) tj[k] = tjs[j * JD + k];

        const float t = tar_conf[b * NQ + j];

        float* outp = out + ((size_t)b * NQ + i0) * NQ + j;
        #pragma unroll
        for (int il = 0; il < ITILE; il++) {
            const float4* prow4 = (const float4*)(pjs + il * JDP);  // 16B-aligned
            // 4-way split accumulators; pjs read as 12 float4 broadcasts + 3 tail
            float s0 = 0.f, s1 = 0.f, s2 = 0.f, s3 = 0.f;
            #pragma unroll
            for (int q = 0; q < JD / 4; q++) {       // 12 vec4 = 48 elems
                float4 p = prow4[q];
                s0 += fabsf(p.x - tj[4 * q + 0]);
                s1 += fabsf(p.y - tj[4 * q + 1]);
                s2 += fabsf(p.z - tj[4 * q + 2]);
                s3 += fabsf(p.w - tj[4 * q + 3]);
            }
            s0 += fabsf(pjs[il * JDP + 48] - tj[48]);
            s1 += fabsf(pjs[il * JDP + 49] - tj[49]);
            s2 += fabsf(pjs[il * JDP + 50] - tj[50]);
            float s = (s0 + s1) + (s2 + s3);
            float cp = -(t * lps[il] + (1.f - t) * l1ps[il]);
            outp[(size_t)il * NQ] = cp + s + rowc[il];
        }
    }
}

extern "C" void kernel_launch(void* const* d_in, const int* in_sizes, int n_in,
                              void* d_out, int out_size, void* d_ws, size_t ws_size,
                              hipStream_t stream) {
    const float* pred_conf   = (const float*)d_in[0];
    const float* pred_joint  = (const float*)d_in[1];
    const float* pred_action = (const float*)d_in[2];
    const float* pred_ident  = (const float*)d_in[3];
    const float* tar_conf    = (const float*)d_in[4];
    const float* tar_joint   = (const float*)d_in[5];
    // d_in[6] (tar_action) and d_in[7] (tar_identity) are unused by the reference cost.
    float* outp = (float*)d_out;

    dim3 grid(BS, NTILES);
    matcher_kernel<<<grid, BLOCK, 0, stream>>>(
        pred_conf, pred_joint, pred_action, pred_ident, tar_conf, tar_joint, outp);
}